// Round 2
// baseline (140.556 us; speedup 1.0000x reference)
//
#include <hip/hip_runtime.h>

#define BB 4
#define NN 1024
#define EE 32
#define BLOCK 256
#define JPT (NN / BLOCK)   // j's per thread = 4

__global__ __launch_bounds__(BLOCK) void anchor_loss_kernel(
    const float* __restrict__ emb,          // [B,N,E]
    const float* __restrict__ coords,       // [B,N,2]
    const int*   __restrict__ mask,         // [B,N,N] bool -> int32
    float* __restrict__ out)
{
    const int row = blockIdx.x;       // b*N + i
    const int b   = row >> 10;
    const int i   = row & (NN - 1);
    const int tid = threadIdx.x;

    __shared__ float yi_s[EE];
    __shared__ float red[BLOCK / 64];

    // stage y_i = emb_i (+ coords on first two dims)
    if (tid < EE) {
        float v = emb[(size_t)row * EE + tid];
        if (tid < 2) v += coords[(size_t)row * 2 + tid];
        yi_s[tid] = v;
    }
    __syncthreads();

    float yil[EE];
    #pragma unroll
    for (int e = 0; e < EE; ++e) yil[e] = yi_s[e];

    const float* embb = emb    + (size_t)b * NN * EE;
    const float* crdb = coords + (size_t)b * NN * 2;
    const int*   mrow = mask   + (size_t)row * NN;

    float siml[JPT];
    int   ml[JPT];
    float sum_exp = 0.0f;

    #pragma unroll
    for (int k = 0; k < JPT; ++k) {
        const int j = tid + k * BLOCK;
        const float4* yj4 = (const float4*)(embb + (size_t)j * EE);
        const float c0 = crdb[j * 2 + 0];
        const float c1 = crdb[j * 2 + 1];
        float ssq = 0.0f;
        #pragma unroll
        for (int q = 0; q < EE / 4; ++q) {
            float4 v = yj4[q];
            float d0 = yil[q * 4 + 0] - v.x;
            float d1 = yil[q * 4 + 1] - v.y;
            float d2 = yil[q * 4 + 2] - v.z;
            float d3 = yil[q * 4 + 3] - v.w;
            if (q == 0) { d0 -= c0; d1 -= c1; }   // y_j first two dims carry coords
            ssq += d0 * d0 + d1 * d1 + d2 * d2 + d3 * d3;
        }
        const float dist = sqrtf(ssq);
        // sim = 1 - sigmoid(dist - 5) = 1 / (1 + exp(dist - 5))
        const float sim = 1.0f / (1.0f + __expf(dist - 5.0f));
        const int m = mrow[j];
        siml[k] = sim;
        ml[k]   = m;
        const bool negm = (m != 0) || (j == i);
        sum_exp += negm ? 0.0f : __expf(sim);
    }

    // block reduction of sum_exp (wave=64 shuffle, then LDS across 4 waves)
    #pragma unroll
    for (int off = 32; off > 0; off >>= 1)
        sum_exp += __shfl_down(sum_exp, off, 64);
    if ((tid & 63) == 0) red[tid >> 6] = sum_exp;
    __syncthreads();
    const float total   = red[0] + red[1] + red[2] + red[3];
    const float lse_neg = logf(total);   // -inf if all masked -> log1p(exp(-inf))=0

    __syncthreads();   // red[] reused below

    // pass 2: positive-pair contributions: log1p(exp(lse_neg - sim))
    float acc = 0.0f;
    #pragma unroll
    for (int k = 0; k < JPT; ++k) {
        if (ml[k] != 0) {
            const float x = lse_neg - siml[k];
            acc += log1pf(__expf(x));
        }
    }

    #pragma unroll
    for (int off = 32; off > 0; off >>= 1)
        acc += __shfl_down(acc, off, 64);
    if ((tid & 63) == 0) red[tid >> 6] = acc;
    __syncthreads();
    if (tid == 0) {
        atomicAdd(out, red[0] + red[1] + red[2] + red[3]);
    }
}

extern "C" void kernel_launch(void* const* d_in, const int* in_sizes, int n_in,
                              void* d_out, int out_size, void* d_ws, size_t ws_size,
                              hipStream_t stream) {
    const float* emb    = (const float*)d_in[0];
    const float* coords = (const float*)d_in[1];
    const int*   mask   = (const int*)d_in[2];
    float*       out    = (float*)d_out;

    // d_out is poisoned 0xAA before every timed call -> zero it (capture-safe)
    hipMemsetAsync(out, 0, sizeof(float), stream);

    anchor_loss_kernel<<<BB * NN, BLOCK, 0, stream>>>(emb, coords, mask, out);
}

// Round 3
// 108.491 us; speedup vs baseline: 1.2956x; 1.2956x over previous
//
#include <hip/hip_runtime.h>

#define BB 4
#define NN 1024
#define EE 32
#define BLOCK 256
#define TI 4                 // i-rows per block
#define CHUNK 256            // j-rows staged per LDS chunk
#define NCHUNK (NN / CHUNK)  // 4

__global__ __launch_bounds__(BLOCK, 4) void anchor_loss_kernel(
    const float* __restrict__ emb,     // [B,N,E]
    const float* __restrict__ coords,  // [B,N,2]
    const int*   __restrict__ mask,    // [B,N,N] bool -> int32
    float* __restrict__ out)
{
    const int bid = blockIdx.x;        // B * (N/TI) = 1024 blocks
    const int b   = bid >> 8;
    const int it  = bid & 255;
    const int i0  = it * TI;
    const int tid = threadIdx.x;

    __shared__ float yj_s[CHUNK * EE];   // 32 KB, XOR-swizzled quads
    __shared__ float yi_s[TI][EE];
    __shared__ float ni_s[TI];
    __shared__ float wred[4][TI];
    __shared__ float wred2[4];

    const float* embb = emb    + (size_t)b * NN * EE;
    const float* crdb = coords + (size_t)b * NN * 2;

    // stage y_i rows (emb + coords folded into dims 0,1)
    if (tid < TI * EE) {
        const int r = tid >> 5, e = tid & 31;
        float v = embb[(i0 + r) * EE + e];
        if (e < 2) v += crdb[(i0 + r) * 2 + e];
        yi_s[r][e] = v;
    }
    __syncthreads();
    if (tid < TI) {
        float s = 0.f;
        #pragma unroll
        for (int e = 0; e < EE; ++e) { const float v = yi_s[tid][e]; s += v * v; }
        ni_s[tid] = s;
    }

    float    siml[NCHUNK][TI];
    float    sum_part[TI];
    unsigned mbits = 0u;
    #pragma unroll
    for (int i = 0; i < TI; ++i) sum_part[i] = 0.f;

    for (int c = 0; c < NCHUNK; ++c) {
        __syncthreads();   // yj_s reuse guard (also publishes yi_s/ni_s on c==0)

        // coalesced global -> LDS staging of 256 y_j rows, XOR-swizzled
        const float4* src4 = (const float4*)embb + (size_t)c * CHUNK * (EE / 4);
        #pragma unroll
        for (int w = 0; w < (CHUNK * EE / 4) / BLOCK; ++w) {   // 8 float4 / thread
            const int g = w * BLOCK + tid;                     // 0..2047
            const int r = g >> 3, q = g & 7;
            float4 v = src4[g];
            if (q == 0) {  // fold coords into dims 0,1
                v.x += crdb[(c * CHUNK + r) * 2 + 0];
                v.y += crdb[(c * CHUNK + r) * 2 + 1];
            }
            ((float4*)yj_s)[r * 8 + (q ^ (r & 7))] = v;
        }
        __syncthreads();

        // own y_j row -> registers (swizzled b128 reads, conflict-floor)
        float rj[EE];
        #pragma unroll
        for (int q = 0; q < 8; ++q) {
            const float4 v = ((const float4*)yj_s)[tid * 8 + (q ^ (tid & 7))];
            rj[q * 4 + 0] = v.x; rj[q * 4 + 1] = v.y;
            rj[q * 4 + 2] = v.z; rj[q * 4 + 3] = v.w;
        }
        float nj = 0.f;
        #pragma unroll
        for (int e = 0; e < EE; ++e) nj += rj[e] * rj[e];

        const int j = c * CHUNK + tid;
        #pragma unroll
        for (int i = 0; i < TI; ++i) {
            const float4* yi4 = (const float4*)yi_s[i];   // broadcast reads
            float dot = 0.f;
            #pragma unroll
            for (int q = 0; q < 8; ++q) {
                const float4 u = yi4[q];
                dot += u.x * rj[q * 4 + 0] + u.y * rj[q * 4 + 1]
                     + u.z * rj[q * 4 + 2] + u.w * rj[q * 4 + 3];
            }
            float ssq = ni_s[i] + nj - 2.f * dot;
            ssq = fmaxf(ssq, 0.f);                         // cancellation/diag guard
            const float dist = sqrtf(ssq);
            const float sim  = 1.f / (1.f + __expf(dist - 5.f));
            const int   m    = mask[(size_t)(b * NN + i0 + i) * NN + j];
            const bool  negm = (m != 0) || (j == i0 + i);
            sum_part[i] += negm ? 0.f : __expf(sim);
            siml[c][i] = sim;
            if (m != 0) mbits |= 1u << (c * TI + i);
        }
    }

    // block-reduce sum_part[i] over 256 threads
    #pragma unroll
    for (int i = 0; i < TI; ++i) {
        float s = sum_part[i];
        #pragma unroll
        for (int off = 32; off > 0; off >>= 1) s += __shfl_down(s, off, 64);
        if ((tid & 63) == 0) wred[tid >> 6][i] = s;
    }
    __syncthreads();
    float lse[TI];
    #pragma unroll
    for (int i = 0; i < TI; ++i)
        lse[i] = logf(wred[0][i] + wred[1][i] + wred[2][i] + wred[3][i]);
    // all-masked row: total=0 -> lse=-inf -> exp(-inf)=0 -> log1p(0)=0  (correct)

    // pass 2: positive pairs, loss = log1p(exp(lse_neg - sim))
    float acc = 0.f;
    #pragma unroll
    for (int c = 0; c < NCHUNK; ++c)
        #pragma unroll
        for (int i = 0; i < TI; ++i)
            if ((mbits >> (c * TI + i)) & 1u)
                acc += log1pf(__expf(lse[i] - siml[c][i]));

    #pragma unroll
    for (int off = 32; off > 0; off >>= 1) acc += __shfl_down(acc, off, 64);
    if ((tid & 63) == 0) wred2[tid >> 6] = acc;
    __syncthreads();
    if (tid == 0) atomicAdd(out, wred2[0] + wred2[1] + wred2[2] + wred2[3]);
}

extern "C" void kernel_launch(void* const* d_in, const int* in_sizes, int n_in,
                              void* d_out, int out_size, void* d_ws, size_t ws_size,
                              hipStream_t stream) {
    const float* emb    = (const float*)d_in[0];
    const float* coords = (const float*)d_in[1];
    const int*   mask   = (const int*)d_in[2];
    float*       out    = (float*)d_out;

    hipMemsetAsync(out, 0, sizeof(float), stream);  // d_out is 0xAA-poisoned
    anchor_loss_kernel<<<BB * (NN / TI), BLOCK, 0, stream>>>(emb, coords, mask, out);
}